// Round 2
// baseline (359.298 us; speedup 1.0000x reference)
//
#include <hip/hip_runtime.h>
#include <math.h>

// Fixed problem dims from setup_inputs()
#define BATCH 2
#define C 64
#define HIN 128
#define WIN 128
#define OH 256
#define OW 256
#define SCALE 2.0f

// __launch_bounds__(256, 2): min 2 waves/EU -> VGPR cap 256. Round-1 showed
// the default heuristic spilled the per-thread float arrays to scratch
// (VGPR_Count=72, occupancy 23%, 250us). Peak live set here is
// pf[64]+h1[64] (~160 VGPR) which must stay in registers.
__global__ __launch_bounds__(256, 2) void scab_kernel(
    const float* __restrict__ x,    // (B, C, HIN, WIN)
    const float* __restrict__ wcm,  // weight_compress (4, 8, 64)
    const float* __restrict__ wex,  // weight_expand   (4, 64, 8)
    const float* __restrict__ w1,   // (64, 68)
    const float* __restrict__ b1,   // (64)
    const float* __restrict__ w2,   // (64, 64)
    const float* __restrict__ b2,   // (64)
    const float* __restrict__ wr,   // (4, 64)
    const float* __restrict__ br,   // (4)
    const float* __restrict__ wo,   // (2, 64)
    const float* __restrict__ bo,   // (2)
    float* __restrict__ out)        // (B, C, OH, OW)
{
    const int p  = blockIdx.x * 256 + threadIdx.x;
    const int ox = p & (OW - 1);
    const int oy = (p >> 8) & (OH - 1);
    const int bb = p >> 16;

    // ---- coords channels (match reference exactly) ----
    const float c01 = 1.0f / SCALE;
    const float fh = (oy + 0.5f) / SCALE;
    const float coor_h = fh - floorf(fh + 0.001f) - 0.5f;
    const float fw = (ox + 0.5f) / SCALE;
    const float coor_w = fw - floorf(fw + 0.001f) - 0.5f;

    // ---- base grid (make_grid without offset) ----
    const float gx = ((ox + 0.5f) / SCALE - 0.5f) * (2.0f / (WIN - 1)) - 1.0f;
    const float gy = ((oy + 0.5f) / SCALE - 0.5f) * (2.0f / (HIN - 1)) - 1.0f;

    const float* __restrict__ xb = x + bb * (C * HIN * WIN);

    // ================= sampling 1: pre_fea =================
    float pf[C];
    {
        const float fx = ((gx + 1.0f) * WIN - 1.0f) * 0.5f;
        const float fy = ((gy + 1.0f) * HIN - 1.0f) * 0.5f;
        const float x0 = floorf(fx), y0 = floorf(fy);
        const float wx1 = fx - x0, wx0 = 1.0f - wx1;
        const float wy1 = fy - y0, wy0 = 1.0f - wy1;
        const float x1 = x0 + 1.0f, y1 = y0 + 1.0f;
        const bool vx0 = (x0 >= 0.0f) && (x0 <= (float)(WIN - 1));
        const bool vx1 = (x1 >= 0.0f) && (x1 <= (float)(WIN - 1));
        const bool vy0 = (y0 >= 0.0f) && (y0 <= (float)(HIN - 1));
        const bool vy1 = (y1 >= 0.0f) && (y1 <= (float)(HIN - 1));
        const int xi0 = (int)fminf(fmaxf(x0, 0.0f), (float)(WIN - 1));
        const int xi1 = (int)fminf(fmaxf(x1, 0.0f), (float)(WIN - 1));
        const int yi0 = (int)fminf(fmaxf(y0, 0.0f), (float)(HIN - 1));
        const int yi1 = (int)fminf(fmaxf(y1, 0.0f), (float)(HIN - 1));
        const float w00 = wx0 * wy0 * ((vx0 && vy0) ? 1.0f : 0.0f);
        const float w10 = wx1 * wy0 * ((vx1 && vy0) ? 1.0f : 0.0f);
        const float w01 = wx0 * wy1 * ((vx0 && vy1) ? 1.0f : 0.0f);
        const float w11 = wx1 * wy1 * ((vx1 && vy1) ? 1.0f : 0.0f);
        const int i00 = yi0 * WIN + xi0;
        const int i10 = yi0 * WIN + xi1;
        const int i01 = yi1 * WIN + xi0;
        const int i11 = yi1 * WIN + xi1;
        #pragma unroll
        for (int c = 0; c < C; ++c) {
            const float* __restrict__ xc = xb + c * (HIN * WIN);
            pf[c] = xc[i00] * w00 + xc[i10] * w10 + xc[i01] * w01 + xc[i11] * w11;
        }
    }

    // ================= conv1 (68 -> 64) + ReLU =================
    float h1[C];
    #pragma unroll
    for (int o = 0; o < C; ++o) {
        const float* __restrict__ wrow = w1 + o * (C + 4);
        float acc = b1[o];
        acc = fmaf(wrow[0], c01, acc);
        acc = fmaf(wrow[1], c01, acc);
        acc = fmaf(wrow[2], coor_h, acc);
        acc = fmaf(wrow[3], coor_w, acc);
        #pragma unroll
        for (int c = 0; c < C; ++c) acc = fmaf(wrow[4 + c], pf[c], acc);
        h1[o] = fmaxf(acc, 0.0f);
    }
    // pf dead here.

    // ====== conv2 (64 -> 64) + ReLU, fused with offset/gate heads ======
    // emb[o] is consumed immediately by the 6 head accumulators, never
    // stored as an array -> peak live stays at h1[64] + 6.
    float offx = bo[0], offy = bo[1];
    float z0 = br[0], z1 = br[1], z2 = br[2], z3 = br[3];
    #pragma unroll
    for (int o = 0; o < C; ++o) {
        const float* __restrict__ wrow = w2 + o * C;
        float acc = b2[o];
        #pragma unroll
        for (int c = 0; c < C; ++c) acc = fmaf(wrow[c], h1[c], acc);
        const float e = fmaxf(acc, 0.0f);
        offx = fmaf(wo[o],         e, offx);
        offy = fmaf(wo[C + o],     e, offy);
        z0   = fmaf(wr[o],         e, z0);
        z1   = fmaf(wr[C + o],     e, z1);
        z2   = fmaf(wr[2 * C + o], e, z2);
        z3   = fmaf(wr[3 * C + o], e, z3);
    }
    // h1 dead here.

    float rg0 = 1.0f / (1.0f + __expf(-z0));
    float rg1 = 1.0f / (1.0f + __expf(-z1));
    float rg2 = 1.0f / (1.0f + __expf(-z2));
    float rg3 = 1.0f / (1.0f + __expf(-z3));

    // ================= sampling 2: fea0 (with offset) =================
    float fea0[C];
    {
        const float ix2 = gx + offx * (2.0f / (WIN - 1));
        const float iy2 = gy + offy * (2.0f / (HIN - 1));
        const float fx = ((ix2 + 1.0f) * WIN - 1.0f) * 0.5f;
        const float fy = ((iy2 + 1.0f) * HIN - 1.0f) * 0.5f;
        const float x0 = floorf(fx), y0 = floorf(fy);
        const float wx1 = fx - x0, wx0 = 1.0f - wx1;
        const float wy1 = fy - y0, wy0 = 1.0f - wy1;
        const float x1 = x0 + 1.0f, y1 = y0 + 1.0f;
        const bool vx0 = (x0 >= 0.0f) && (x0 <= (float)(WIN - 1));
        const bool vx1 = (x1 >= 0.0f) && (x1 <= (float)(WIN - 1));
        const bool vy0 = (y0 >= 0.0f) && (y0 <= (float)(HIN - 1));
        const bool vy1 = (y1 >= 0.0f) && (y1 <= (float)(HIN - 1));
        const int xi0 = (int)fminf(fmaxf(x0, 0.0f), (float)(WIN - 1));
        const int xi1 = (int)fminf(fmaxf(x1, 0.0f), (float)(WIN - 1));
        const int yi0 = (int)fminf(fmaxf(y0, 0.0f), (float)(HIN - 1));
        const int yi1 = (int)fminf(fmaxf(y1, 0.0f), (float)(HIN - 1));
        const float w00 = wx0 * wy0 * ((vx0 && vy0) ? 1.0f : 0.0f);
        const float w10 = wx1 * wy0 * ((vx1 && vy0) ? 1.0f : 0.0f);
        const float w01 = wx0 * wy1 * ((vx0 && vy1) ? 1.0f : 0.0f);
        const float w11 = wx1 * wy1 * ((vx1 && vy1) ? 1.0f : 0.0f);
        const int i00 = yi0 * WIN + xi0;
        const int i10 = yi0 * WIN + xi1;
        const int i01 = yi1 * WIN + xi0;
        const int i11 = yi1 * WIN + xi1;
        #pragma unroll
        for (int c = 0; c < C; ++c) {
            const float* __restrict__ xc = xb + c * (HIN * WIN);
            fea0[c] = xc[i00] * w00 + xc[i10] * w10 + xc[i01] * w01 + xc[i11] * w11;
        }
    }

    // ========= compress: comp[d] = sum_e r[e] * dot(wcm[e,d,:], fea0) =========
    float comp[8];
    #pragma unroll
    for (int d = 0; d < 8; ++d) comp[d] = 0.0f;
    #pragma unroll
    for (int e = 0; e < 4; ++e) {
        const float re = (e == 0) ? rg0 : (e == 1) ? rg1 : (e == 2) ? rg2 : rg3;
        #pragma unroll
        for (int d = 0; d < 8; ++d) {
            const float* __restrict__ wrow = wcm + (e * 8 + d) * C;
            float acc = 0.0f;
            #pragma unroll
            for (int c = 0; c < C; ++c) acc = fmaf(wrow[c], fea0[c], acc);
            comp[d] = fmaf(re, acc, comp[d]);
        }
    }

    // ==== expand + residual: out[c] = fea0[c] + sum_e r[e]*dot(wex[e,c,:], comp) ====
    float* __restrict__ ob = out + bb * (C * OH * OW) + oy * OW + ox;
    #pragma unroll
    for (int c = 0; c < C; ++c) {
        float acc = 0.0f;
        #pragma unroll
        for (int e = 0; e < 4; ++e) {
            const float re = (e == 0) ? rg0 : (e == 1) ? rg1 : (e == 2) ? rg2 : rg3;
            const float* __restrict__ wrow = wex + (e * C + c) * 8;
            float s = 0.0f;
            #pragma unroll
            for (int d = 0; d < 8; ++d) s = fmaf(wrow[d], comp[d], s);
            acc = fmaf(re, s, acc);
        }
        ob[c * (OH * OW)] = acc + fea0[c];
    }
}

extern "C" void kernel_launch(void* const* d_in, const int* in_sizes, int n_in,
                              void* d_out, int out_size, void* d_ws, size_t ws_size,
                              hipStream_t stream) {
    const float* x   = (const float*)d_in[0];
    const float* wcm = (const float*)d_in[1];
    const float* wex = (const float*)d_in[2];
    const float* w1  = (const float*)d_in[3];
    const float* b1  = (const float*)d_in[4];
    const float* w2  = (const float*)d_in[5];
    const float* b2  = (const float*)d_in[6];
    const float* wr  = (const float*)d_in[7];
    const float* br  = (const float*)d_in[8];
    const float* wo  = (const float*)d_in[9];
    const float* bo  = (const float*)d_in[10];
    float* out = (float*)d_out;

    const int total = BATCH * OH * OW;           // 131072 pixels
    const int blocks = total / 256;              // 512 blocks
    scab_kernel<<<blocks, 256, 0, stream>>>(x, wcm, wex, w1, b1, w2, b2,
                                            wr, br, wo, bo, out);
}

// Round 3
// 181.947 us; speedup vs baseline: 1.9747x; 1.9747x over previous
//
#include <hip/hip_runtime.h>
#include <math.h>

// Fixed problem dims from setup_inputs()
#define BATCH 2
#define C 64
#define HIN 128
#define WIN 128
#define OH 256
#define OW 256
#define SCALE 2.0f

// Structure notes (round 3):
//  - NO dynamically-indexed per-thread arrays. Rounds 1-2 spilled because
//    4096-stmt outer unrolls were refused by clang, leaving runtime indices
//    into pf[]/h1[] -> scratch (VGPR=72, 250-360us, VALUBusy 18%).
//  - conv1: accumulator form (rolled c, unrolled o: h1[o] += w1[o][c]*pf_c),
//    pf never materialized. conv2: dot form (rolled o, unrolled c over h1),
//    outputs are 6 scalars. compress: accumulator into comp[8]. expand:
//    dot form per channel, fea0_c recomputed (cache-hot reloads).
//  - Occupancy is grid-limited at 8 waves/CU (2048 waves total), so each
//    sampling loop prefetches the next channel's 4 loads for ILP.
__global__ __launch_bounds__(256, 2) void scab_kernel(
    const float* __restrict__ x,    // (B, C, HIN, WIN)
    const float* __restrict__ wcm,  // weight_compress (4, 8, 64)
    const float* __restrict__ wex,  // weight_expand   (4, 64, 8)
    const float* __restrict__ w1,   // (64, 68)
    const float* __restrict__ b1,   // (64)
    const float* __restrict__ w2,   // (64, 64)
    const float* __restrict__ b2,   // (64)
    const float* __restrict__ wr,   // (4, 64)
    const float* __restrict__ br,   // (4)
    const float* __restrict__ wo,   // (2, 64)
    const float* __restrict__ bo,   // (2)
    float* __restrict__ out)        // (B, C, OH, OW)
{
    const int p  = blockIdx.x * 256 + threadIdx.x;
    const int ox = p & (OW - 1);
    const int oy = (p >> 8) & (OH - 1);
    const int bb = p >> 16;

    // ---- coords channels (match reference exactly) ----
    const float c01 = 1.0f / SCALE;
    const float fh = (oy + 0.5f) / SCALE;
    const float coor_h = fh - floorf(fh + 0.001f) - 0.5f;
    const float fw = (ox + 0.5f) / SCALE;
    const float coor_w = fw - floorf(fw + 0.001f) - 0.5f;

    // ---- base grid (make_grid without offset) ----
    const float gx = ((ox + 0.5f) / SCALE - 0.5f) * (2.0f / (WIN - 1)) - 1.0f;
    const float gy = ((oy + 0.5f) / SCALE - 0.5f) * (2.0f / (HIN - 1)) - 1.0f;

    const float* __restrict__ xb = x + bb * (C * HIN * WIN);

    // ---- sampling-1 indices & bilinear weights (per pixel, no offset) ----
    int i00, i10, i01, i11;
    float w00, w10, w01, w11;
    {
        const float fx = ((gx + 1.0f) * WIN - 1.0f) * 0.5f;
        const float fy = ((gy + 1.0f) * HIN - 1.0f) * 0.5f;
        const float x0 = floorf(fx), y0 = floorf(fy);
        const float wx1 = fx - x0, wx0 = 1.0f - wx1;
        const float wy1 = fy - y0, wy0 = 1.0f - wy1;
        const float x1 = x0 + 1.0f, y1 = y0 + 1.0f;
        const bool vx0 = (x0 >= 0.0f) && (x0 <= (float)(WIN - 1));
        const bool vx1 = (x1 >= 0.0f) && (x1 <= (float)(WIN - 1));
        const bool vy0 = (y0 >= 0.0f) && (y0 <= (float)(HIN - 1));
        const bool vy1 = (y1 >= 0.0f) && (y1 <= (float)(HIN - 1));
        const int xi0 = (int)fminf(fmaxf(x0, 0.0f), (float)(WIN - 1));
        const int xi1 = (int)fminf(fmaxf(x1, 0.0f), (float)(WIN - 1));
        const int yi0 = (int)fminf(fmaxf(y0, 0.0f), (float)(HIN - 1));
        const int yi1 = (int)fminf(fmaxf(y1, 0.0f), (float)(HIN - 1));
        w00 = wx0 * wy0 * ((vx0 && vy0) ? 1.0f : 0.0f);
        w10 = wx1 * wy0 * ((vx1 && vy0) ? 1.0f : 0.0f);
        w01 = wx0 * wy1 * ((vx0 && vy1) ? 1.0f : 0.0f);
        w11 = wx1 * wy1 * ((vx1 && vy1) ? 1.0f : 0.0f);
        i00 = yi0 * WIN + xi0;
        i10 = yi0 * WIN + xi1;
        i01 = yi1 * WIN + xi0;
        i11 = yi1 * WIN + xi1;
    }

    // ===== conv1 accumulators: init with bias + coord terms =====
    float h1[C];
    #pragma unroll
    for (int o = 0; o < C; ++o) {
        const float* __restrict__ wrow = w1 + o * (C + 4);
        float a = b1[o];
        a = fmaf(wrow[0], c01, a);
        a = fmaf(wrow[1], c01, a);
        a = fmaf(wrow[2], coor_h, a);
        a = fmaf(wrow[3], coor_w, a);
        h1[o] = a;
    }

    // ===== fused sampling-1 + conv1 (accumulator form, rolled c) =====
    {
        const float* __restrict__ xc0 = xb;
        float l00 = xc0[i00], l10 = xc0[i10], l01 = xc0[i01], l11 = xc0[i11];
        for (int c = 0; c < C; ++c) {
            const int cn = (c < C - 1) ? (c + 1) : c;
            const float* __restrict__ xn = xb + cn * (HIN * WIN);
            const float n00 = xn[i00], n10 = xn[i10], n01 = xn[i01], n11 = xn[i11];
            const float pfc = l00 * w00 + l10 * w10 + l01 * w01 + l11 * w11;
            const float* __restrict__ wcol = w1 + 4 + c;   // column, stride 68
            #pragma unroll
            for (int o = 0; o < C; ++o)
                h1[o] = fmaf(wcol[o * (C + 4)], pfc, h1[o]);
            l00 = n00; l10 = n10; l01 = n01; l11 = n11;
        }
        #pragma unroll
        for (int o = 0; o < C; ++o) h1[o] = fmaxf(h1[o], 0.0f);
    }

    // ===== conv2 + heads (dot form, rolled o, unrolled c over h1) =====
    float offx = bo[0], offy = bo[1];
    float z0 = br[0], z1 = br[1], z2 = br[2], z3 = br[3];
    for (int o = 0; o < C; ++o) {
        const float* __restrict__ wrow = w2 + o * C;   // contiguous row
        float acc = b2[o];
        #pragma unroll
        for (int c = 0; c < C; ++c) acc = fmaf(wrow[c], h1[c], acc);
        const float e = fmaxf(acc, 0.0f);
        offx = fmaf(wo[o],         e, offx);
        offy = fmaf(wo[C + o],     e, offy);
        z0   = fmaf(wr[o],         e, z0);
        z1   = fmaf(wr[C + o],     e, z1);
        z2   = fmaf(wr[2 * C + o], e, z2);
        z3   = fmaf(wr[3 * C + o], e, z3);
    }

    const float rg0 = 1.0f / (1.0f + __expf(-z0));
    const float rg1 = 1.0f / (1.0f + __expf(-z1));
    const float rg2 = 1.0f / (1.0f + __expf(-z2));
    const float rg3 = 1.0f / (1.0f + __expf(-z3));

    // ---- sampling-2 indices & weights (with offset) ----
    int j00, j10, j01, j11;
    float v00, v10, v01, v11;
    {
        const float ix2 = gx + offx * (2.0f / (WIN - 1));
        const float iy2 = gy + offy * (2.0f / (HIN - 1));
        const float fx = ((ix2 + 1.0f) * WIN - 1.0f) * 0.5f;
        const float fy = ((iy2 + 1.0f) * HIN - 1.0f) * 0.5f;
        const float x0 = floorf(fx), y0 = floorf(fy);
        const float wx1 = fx - x0, wx0 = 1.0f - wx1;
        const float wy1 = fy - y0, wy0 = 1.0f - wy1;
        const float x1 = x0 + 1.0f, y1 = y0 + 1.0f;
        const bool vx0 = (x0 >= 0.0f) && (x0 <= (float)(WIN - 1));
        const bool vx1 = (x1 >= 0.0f) && (x1 <= (float)(WIN - 1));
        const bool vy0 = (y0 >= 0.0f) && (y0 <= (float)(HIN - 1));
        const bool vy1 = (y1 >= 0.0f) && (y1 <= (float)(HIN - 1));
        const int xi0 = (int)fminf(fmaxf(x0, 0.0f), (float)(WIN - 1));
        const int xi1 = (int)fminf(fmaxf(x1, 0.0f), (float)(WIN - 1));
        const int yi0 = (int)fminf(fmaxf(y0, 0.0f), (float)(HIN - 1));
        const int yi1 = (int)fminf(fmaxf(y1, 0.0f), (float)(HIN - 1));
        v00 = wx0 * wy0 * ((vx0 && vy0) ? 1.0f : 0.0f);
        v10 = wx1 * wy0 * ((vx1 && vy0) ? 1.0f : 0.0f);
        v01 = wx0 * wy1 * ((vx0 && vy1) ? 1.0f : 0.0f);
        v11 = wx1 * wy1 * ((vx1 && vy1) ? 1.0f : 0.0f);
        j00 = yi0 * WIN + xi0;
        j10 = yi0 * WIN + xi1;
        j01 = yi1 * WIN + xi0;
        j11 = yi1 * WIN + xi1;
    }

    // ===== fused sampling-2 + compress (accumulator into comp[8]) =====
    float comp[8];
    #pragma unroll
    for (int d = 0; d < 8; ++d) comp[d] = 0.0f;
    {
        const float* __restrict__ xc0 = xb;
        float l00 = xc0[j00], l10 = xc0[j10], l01 = xc0[j01], l11 = xc0[j11];
        for (int c = 0; c < C; ++c) {
            const int cn = (c < C - 1) ? (c + 1) : c;
            const float* __restrict__ xn = xb + cn * (HIN * WIN);
            const float n00 = xn[j00], n10 = xn[j10], n01 = xn[j01], n11 = xn[j11];
            const float fc = l00 * v00 + l10 * v10 + l01 * v01 + l11 * v11;
            const float s0 = rg0 * fc, s1 = rg1 * fc, s2 = rg2 * fc, s3 = rg3 * fc;
            #pragma unroll
            for (int d = 0; d < 8; ++d) {
                comp[d] = fmaf(wcm[(0 * 8 + d) * C + c], s0, comp[d]);
                comp[d] = fmaf(wcm[(1 * 8 + d) * C + c], s1, comp[d]);
                comp[d] = fmaf(wcm[(2 * 8 + d) * C + c], s2, comp[d]);
                comp[d] = fmaf(wcm[(3 * 8 + d) * C + c], s3, comp[d]);
            }
            l00 = n00; l10 = n10; l01 = n01; l11 = n11;
        }
    }

    // ===== expand + residual (dot form per channel, fea0 recomputed) =====
    float* __restrict__ ob = out + bb * (C * OH * OW) + oy * OW + ox;
    {
        const float* __restrict__ xc0 = xb;
        float l00 = xc0[j00], l10 = xc0[j10], l01 = xc0[j01], l11 = xc0[j11];
        for (int c = 0; c < C; ++c) {
            const int cn = (c < C - 1) ? (c + 1) : c;
            const float* __restrict__ xn = xb + cn * (HIN * WIN);
            const float n00 = xn[j00], n10 = xn[j10], n01 = xn[j01], n11 = xn[j11];
            const float fc = l00 * v00 + l10 * v10 + l01 * v01 + l11 * v11;
            float s0 = 0.0f, s1 = 0.0f, s2 = 0.0f, s3 = 0.0f;
            const float* __restrict__ we0 = wex + (0 * C + c) * 8;
            const float* __restrict__ we1 = wex + (1 * C + c) * 8;
            const float* __restrict__ we2 = wex + (2 * C + c) * 8;
            const float* __restrict__ we3 = wex + (3 * C + c) * 8;
            #pragma unroll
            for (int d = 0; d < 8; ++d) {
                s0 = fmaf(we0[d], comp[d], s0);
                s1 = fmaf(we1[d], comp[d], s1);
                s2 = fmaf(we2[d], comp[d], s2);
                s3 = fmaf(we3[d], comp[d], s3);
            }
            float acc = fc;
            acc = fmaf(rg0, s0, acc);
            acc = fmaf(rg1, s1, acc);
            acc = fmaf(rg2, s2, acc);
            acc = fmaf(rg3, s3, acc);
            ob[c * (OH * OW)] = acc;
            l00 = n00; l10 = n10; l01 = n01; l11 = n11;
        }
    }
}

extern "C" void kernel_launch(void* const* d_in, const int* in_sizes, int n_in,
                              void* d_out, int out_size, void* d_ws, size_t ws_size,
                              hipStream_t stream) {
    const float* x   = (const float*)d_in[0];
    const float* wcm = (const float*)d_in[1];
    const float* wex = (const float*)d_in[2];
    const float* w1  = (const float*)d_in[3];
    const float* b1  = (const float*)d_in[4];
    const float* w2  = (const float*)d_in[5];
    const float* b2  = (const float*)d_in[6];
    const float* wr  = (const float*)d_in[7];
    const float* br  = (const float*)d_in[8];
    const float* wo  = (const float*)d_in[9];
    const float* bo  = (const float*)d_in[10];
    float* out = (float*)d_out;

    const int total = BATCH * OH * OW;           // 131072 pixels
    const int blocks = total / 256;              // 512 blocks
    scab_kernel<<<blocks, 256, 0, stream>>>(x, wcm, wex, w1, b1, w2, b2,
                                            wr, br, wo, bo, out);
}